// Round 1
// baseline (207.652 us; speedup 1.0000x reference)
//
#include <hip/hip_runtime.h>
#include <hip/hip_bf16.h>
#include <math.h>

#define BLOCK 256
#define RB 32          // rows per block
#define BD 64          // D-chunk (K-tile)
#define NE 64          // experts
#define DDIM 2048
#define TOPK 8
#define WPITCH 68      // 68*4=272B rows: 16B-aligned, b128 reads hit all 32 banks

__global__ __launch_bounds__(BLOCK, 2) void gate_kernel(
    const float* __restrict__ x,      // [NR, D]
    const float* __restrict__ w,      // [E, D]
    const float* __restrict__ bias,   // [E]
    float* __restrict__ out_w,        // [NR, K] weights
    float* __restrict__ out_i,        // [NR, K] indices (as float)
    int NR)
{
    __shared__ float xs[RB][BD];          // 8 KB
    __shared__ float ws[NE][WPITCH];      // 17 KB
    __shared__ float logits[RB][NE + 1];  // 8.3 KB

    const int t    = threadIdx.x;
    const int e    = t & 63;        // expert owned by this thread
    const int rg   = t >> 6;        // wave id = row group (0..3)
    const int row0 = blockIdx.x * RB;

    float acc[8];
#pragma unroll
    for (int i = 0; i < 8; ++i) acc[i] = 0.f;

    for (int d0 = 0; d0 < DDIM; d0 += BD) {
        // ---- stage x: 32*64 floats = 512 float4, 2 per thread ----
#pragma unroll
        for (int i = 0; i < 2; ++i) {
            int f4 = t + i * BLOCK;            // 0..511
            int r  = f4 >> 4;                  // 16 float4 per row
            int c  = (f4 & 15) << 2;
            float4 v = *(const float4*)&x[(size_t)(row0 + r) * DDIM + d0 + c];
            *(float4*)&xs[r][c] = v;
        }
        // ---- stage w: 64*64 floats = 1024 float4, 4 per thread ----
#pragma unroll
        for (int i = 0; i < 4; ++i) {
            int f4 = t + i * BLOCK;            // 0..1023
            int r  = f4 >> 4;
            int c  = (f4 & 15) << 2;
            float4 v = *(const float4*)&w[(size_t)r * DDIM + d0 + c];
            *(float4*)&ws[r][c] = v;           // (r*68+c)*4 is 16B aligned (c%4==0, 68%4==0)
        }
        __syncthreads();

        // ---- compute: thread = (expert e, 8 rows rg*8..rg*8+7) ----
#pragma unroll
        for (int g = 0; g < 16; ++g) {
            float4 wv = *(const float4*)&ws[e][g * 4];
#pragma unroll
            for (int r = 0; r < 8; ++r) {
                float4 xv = *(const float4*)&xs[rg * 8 + r][g * 4];  // wave-uniform broadcast
                acc[r] += wv.x * xv.x;
                acc[r] += wv.y * xv.y;
                acc[r] += wv.z * xv.z;
                acc[r] += wv.w * xv.w;
            }
        }
        __syncthreads();
    }

    // ---- dump logits to LDS: logits[row][expert] ----
#pragma unroll
    for (int i = 0; i < 8; ++i) logits[rg * 8 + i][e] = acc[i];
    __syncthreads();

    // ---- top-8 per row, one wave per 8 rows, lane = expert ----
    const int lane = e;
    const float bias_l = bias[lane];

    for (int r8 = 0; r8 < 8; ++r8) {
        const int r  = rg * 8 + r8;
        const int gr = row0 + r;
        float raw = logits[r][lane];          // pitch 65 -> 2-way bank alias, free
        float sig = 1.f / (1.f + expf(-raw)); // gate weight for own expert
        float v   = raw + bias_l;             // biased logit (ranking key)

        float wsum = 0.f, myw = 0.f;
        int   myidx = 0;
#pragma unroll
        for (int k = 0; k < TOPK; ++k) {
            float m = v;
#pragma unroll
            for (int off = 32; off; off >>= 1)
                m = fmaxf(m, __shfl_xor(m, off));
            unsigned long long b = __ballot(v == m);
            int idx = (int)__builtin_ctzll(b);          // lowest index wins ties (stable top_k)
            float wk = __shfl(sig, idx);
            wsum += wk;                                  // same order as reference sum
            if (lane == k)  { myw = wk; myidx = idx; }
            if (lane == idx) v = -INFINITY;
        }
        if (lane < TOPK) {
            out_w[(size_t)gr * TOPK + lane] = myw / wsum;
            out_i[(size_t)gr * TOPK + lane] = (float)myidx;
        }
    }
}

extern "C" void kernel_launch(void* const* d_in, const int* in_sizes, int n_in,
                              void* d_out, int out_size, void* d_ws, size_t ws_size,
                              hipStream_t stream) {
    const float* x    = (const float*)d_in[0];
    const float* w    = (const float*)d_in[1];
    const float* bias = (const float*)d_in[2];
    const int NR = in_sizes[0] / DDIM;          // 16384 rows
    float* out   = (float*)d_out;
    float* out_w = out;
    float* out_i = out + (size_t)NR * TOPK;

    dim3 grid(NR / RB), block(BLOCK);
    hipLaunchKernelGGL(gate_kernel, grid, block, 0, stream,
                       x, w, bias, out_w, out_i, NR);
}